// Round 15
// baseline (1093.437 us; speedup 1.0000x reference)
//
#include <hip/hip_runtime.h>
#include <stdint.h>

#define B_  256
#define T_  512
#define H_  128
#define NSW 6

typedef __bf16 bf2_t  __attribute__((ext_vector_type(2)));
typedef int    i32x4  __attribute__((ext_vector_type(4)));
typedef float  f32x4  __attribute__((ext_vector_type(4)));

#define AS1C(p) ((const __attribute__((address_space(1))) void*)(p))
#define AS3C(p) ((__attribute__((address_space(3))) void*)(p))
typedef __attribute__((address_space(3))) char lds_char;

__device__ __forceinline__ unsigned short f2bf(float f){
  unsigned u = __float_as_uint(f);
  unsigned r = u + 0x7FFFu + ((u >> 16) & 1u);
  return (unsigned short)(r >> 16);
}
__device__ __forceinline__ unsigned pack2(float a, float b){
  return (unsigned)f2bf(a) | ((unsigned)f2bf(b) << 16);
}
__device__ __forceinline__ float dot2bf(unsigned wpair, unsigned hpair, float acc){
  return __builtin_amdgcn_fdot2_f32_bf16(__builtin_bit_cast(bf2_t, wpair),
                                         __builtin_bit_cast(bf2_t, hpair), acc, false);
}
// lgkm-only barrier: never drains vmcnt (in-flight LDS-DMA survives)
__device__ __forceinline__ void lds_barrier(){
  asm volatile("s_waitcnt lgkmcnt(0)\ns_barrier" ::: "memory");
}

// int8 per-row quantization. Image layout (byte offsets):
//   sid*49152 + j*6144 + (g*4+kc)*512 + L*8   (j = row>>4, L = q*16 + (row&15))
// holds int8 of W_g[sid][row=16j+(L&15)][k = kc*32 + (L>>4)*8 + 0..7].
// scales[(g*6+s)*128+row] = amax/127^2.
__global__ __launch_bounds__(256) void pack_weights_i8(const float* __restrict__ Wr,
                                                       const float* __restrict__ Wz,
                                                       const float* __restrict__ Wn,
                                                       uint2* __restrict__ dst,
                                                       float* __restrict__ scales){
  int idx = blockIdx.x * 256 + threadIdx.x;     // (gs, row)
  if (idx >= 18 * 128) return;
  int row = idx & 127;
  int gs  = idx >> 7;
  int s = gs % NSW, g = gs / NSW;
  const float* W = (g == 0) ? Wr : (g == 1) ? Wz : Wn;
  const float* src = W + (size_t)s * (H_*H_) + (size_t)row * H_;
  float amax = 0.f;
  for (int j = 0; j < H_; ++j) amax = fmaxf(amax, fabsf(src[j]));
  amax = fmaxf(amax, 1e-20f);
  float inv = 127.f / amax;
  scales[(g * NSW + s) * H_ + row] = amax / 16129.f;
  int j = row >> 4, rr = row & 15;
  for (int kc = 0; kc < 4; ++kc){
    for (int q = 0; q < 4; ++q){
      unsigned b0 = 0, b1 = 0;
      for (int e = 0; e < 8; ++e){
        int k = kc * 32 + q * 8 + e;
        int v = (int)rintf(src[k] * inv);
        v = v > 127 ? 127 : (v < -127 ? -127 : v);
        unsigned bv = (unsigned)(v & 0xFF);
        if (e < 4) b0 |= bv << (8 * e);
        else       b1 |= bv << (8 * (e - 4));
      }
      int L = q * 16 + rr;
      dst[((size_t)(s * 8 + j) * 12 + g * 4 + kc) * 64 + L] = make_uint2(b0, b1);
    }
  }
}

// 512 threads = 8 waves. Wave w owns rows 16w..16w+15 of ALL THREE gates.
// Per step: wave DMAs its own 6-KB next-step slice (per-wave vmcnt pipeline),
// reads 12 A-frags + 4 B(h)-frags via opaque asm, 12 i8 MFMAs, in-register
// epilogue on col-0 lanes, 2 lgkm-only barriers.
__global__ __launch_bounds__(512, 1) void gru_run(const float* __restrict__ stim,
    const int*   __restrict__ swid,  const float* __restrict__ mask,
    const float* __restrict__ Win,   const float* __restrict__ binp,
    const float* __restrict__ b_hr,  const float* __restrict__ b_hz, const float* __restrict__ b_hn,
    const float* __restrict__ Wo,    const float* __restrict__ bo,
    const uint2* __restrict__ Wpk,   const float* __restrict__ Wsc,
    float* __restrict__ out)
{
  const int b    = blockIdx.x;
  const int tid  = threadIdx.x;
  const int w    = tid >> 6;
  const int L    = tid & 63;
  const int quad = L >> 4;
  const bool colv = (L & 15) == 0;

  __shared__ __align__(16) char  s_ring[2][8][6144];   // 96 KB weight double buffer
  __shared__ uint4          s_stim2[T_];               // 8 KB bf16 stim pairs
  __shared__ float          s_mask[T_];                // 2 KB
  __shared__ unsigned short s_sid[T_];                 // 1 KB
  __shared__ float          s_b[3*NSW*H_];             // 9 KB biases [g][s][row]
  __shared__ float          s_scale[3*NSW*H_];         // 9 KB dequant [g][s][row]
  __shared__ float          s_x[3*H_];                 // 1.5 KB input projections
  __shared__ float          s_h[2][H_];                // 1 KB fp32 h (double buffered)
  __shared__ __align__(16) char s_hb8[2][256];         // h int8 [0,128) + zero pad [128,256)

  // ---- init LDS ----
  for (int k = tid; k < T_; k += 512){
    const float* sp = stim + (size_t)b * T_ * 8 + (size_t)k * 8;
    uint4 o;
    o.x = pack2(sp[0], sp[1]); o.y = pack2(sp[2], sp[3]);
    o.z = pack2(sp[4], sp[5]); o.w = pack2(sp[6], sp[7]);
    s_stim2[k] = o;
    s_mask[k] = mask[(size_t)b * T_ + k];
    int ss = swid[(size_t)b * T_ + k];
    s_sid[k] = (unsigned short)(ss < 0 ? 0 : (ss > NSW - 1 ? NSW - 1 : ss));
  }
  for (int k = tid; k < 3 * NSW * H_; k += 512){
    int gg = k / (NSW * H_); int rr = k % (NSW * H_);
    const float* bp = (gg == 0) ? b_hr : (gg == 1) ? b_hz : b_hn;
    s_b[k] = bp[rr];
    s_scale[k] = Wsc[k];
  }
  if (tid < H_){ s_h[0][tid] = 0.f; s_h[1][tid] = 0.f; }
  if (tid < 128) ((int*)s_hb8)[tid] = 0;    // zero both buffers incl pads

  // input-projection row for output row tid (tid<384)
  unsigned winp[4] = {0,0,0,0};
  float binr = 0.f;
  if (tid < 384){
    #pragma unroll
    for (int e = 0; e < 4; ++e)
      winp[e] = pack2(Win[(size_t)tid * 8 + 2*e], Win[(size_t)tid * 8 + 2*e + 1]);
    binr = binp[tid];
  }

  // logit weights: wave 0 -> logit 0, wave 1 -> logit 1
  float wo_a = 0.f, wo_b = 0.f, bo_r = 0.f;
  if (w < 2){
    wo_a = Wo[w * H_ + L];
    wo_b = Wo[w * H_ + 64 + L];
    bo_r = bo[w];
  }

  lds_char* ring3 = (lds_char*)&s_ring[0][0][0];
  const unsigned ring_off = (unsigned)(unsigned long long)ring3;
  const unsigned hb_off   = (unsigned)(unsigned long long)(lds_char*)&s_hb8[0][0];
  const char* gimg = (const char*)Wpk;     // 49152 B per sid
  float* outp = out + (size_t)b * T_ * 2;

  __syncthreads();

  int sc = __builtin_amdgcn_readfirstlane((int)s_sid[0]);
  int sn = __builtin_amdgcn_readfirstlane((int)s_sid[1]);

  // prologue: each wave DMAs its step-0 slice into slot 0
  {
    const char* gp = gimg + (size_t)sc * 49152 + (size_t)w * 6144 + (size_t)L * 16;
    lds_char* lp = ring3 + w * 6144;
    #pragma unroll
    for (int m = 0; m < 6; ++m)
      __builtin_amdgcn_global_load_lds(AS1C(gp + m*1024), AS3C(lp + m*1024), 16, 0, 0);
  }

  #pragma unroll 1
  for (int t = 0; t < T_; ++t){
    const int cur = t & 1, nxt = cur ^ 1;

    // ---- issue next step's slice DMA (slot nxt), per-wave ----
    {
      const char* gp = gimg + (size_t)sn * 49152 + (size_t)w * 6144 + (size_t)L * 16;
      lds_char* lp = ring3 + nxt * 49152 + w * 6144;
      #pragma unroll
      for (int m = 0; m < 6; ++m)
        __builtin_amdgcn_global_load_lds(AS1C(gp + m*1024), AS3C(lp + m*1024), 16, 0, 0);
    }
    // drain this step's batch: it is older than the 6 just issued
    // (+1 logit store for waves 0,1 at t>0). vmcnt FIFO is in-order.
    if (w < 2 && t > 0) asm volatile("s_waitcnt vmcnt(7)" ::: "memory");
    else                asm volatile("s_waitcnt vmcnt(6)" ::: "memory");

    // ---- opaque frag reads: 12 A (own slice) + 4 B (h int8 / zero pad) ----
    unsigned abase = ring_off + (unsigned)(cur * 49152 + w * 6144 + L * 8);
    unsigned hbase = hb_off + (unsigned)(cur * 256 + (colv ? quad * 8 : 128));
    uint2 a0,a1,a2,a3,a4,a5,a6,a7,a8,a9,a10,a11, b0,b1,b2,b3;
    asm volatile(
      "ds_read_b64 %0, %16\n\t"
      "ds_read_b64 %1, %16 offset:512\n\t"
      "ds_read_b64 %2, %16 offset:1024\n\t"
      "ds_read_b64 %3, %16 offset:1536\n\t"
      "ds_read_b64 %4, %16 offset:2048\n\t"
      "ds_read_b64 %5, %16 offset:2560\n\t"
      "ds_read_b64 %6, %16 offset:3072\n\t"
      "ds_read_b64 %7, %16 offset:3584\n\t"
      "ds_read_b64 %8, %16 offset:4096\n\t"
      "ds_read_b64 %9, %16 offset:4608\n\t"
      "ds_read_b64 %10, %16 offset:5120\n\t"
      "ds_read_b64 %11, %16 offset:5632\n\t"
      "ds_read_b64 %12, %17\n\t"
      "ds_read_b64 %13, %17 offset:32\n\t"
      "ds_read_b64 %14, %17 offset:64\n\t"
      "ds_read_b64 %15, %17 offset:96\n\t"
      "s_waitcnt lgkmcnt(0)"
      : "=&v"(a0),"=&v"(a1),"=&v"(a2),"=&v"(a3),"=&v"(a4),"=&v"(a5),
        "=&v"(a6),"=&v"(a7),"=&v"(a8),"=&v"(a9),"=&v"(a10),"=&v"(a11),
        "=&v"(b0),"=&v"(b1),"=&v"(b2),"=&v"(b3)
      : "v"(abase), "v"(hbase)
      : "memory");

    // ---- input projection x (rows 0..383 on waves 0..5) ----
    if (tid < 384){
      uint4 sp = s_stim2[t];
      float x = binr;
      x = dot2bf(winp[0], sp.x, x);
      x = dot2bf(winp[1], sp.y, x);
      x = dot2bf(winp[2], sp.z, x);
      x = dot2bf(winp[3], sp.w, x);
      s_x[tid] = x;
    }

    // ---- 12 MFMAs: gate g accum over kc ----
    long B0 = __builtin_bit_cast(long, b0), B1 = __builtin_bit_cast(long, b1);
    long B2 = __builtin_bit_cast(long, b2), B3 = __builtin_bit_cast(long, b3);
    i32x4 accR = {0,0,0,0}, accZ = {0,0,0,0}, accN = {0,0,0,0};
    accR = __builtin_amdgcn_mfma_i32_16x16x32_i8(__builtin_bit_cast(long, a0), B0, accR, 0,0,0);
    accR = __builtin_amdgcn_mfma_i32_16x16x32_i8(__builtin_bit_cast(long, a1), B1, accR, 0,0,0);
    accR = __builtin_amdgcn_mfma_i32_16x16x32_i8(__builtin_bit_cast(long, a2), B2, accR, 0,0,0);
    accR = __builtin_amdgcn_mfma_i32_16x16x32_i8(__builtin_bit_cast(long, a3), B3, accR, 0,0,0);
    accZ = __builtin_amdgcn_mfma_i32_16x16x32_i8(__builtin_bit_cast(long, a4), B0, accZ, 0,0,0);
    accZ = __builtin_amdgcn_mfma_i32_16x16x32_i8(__builtin_bit_cast(long, a5), B1, accZ, 0,0,0);
    accZ = __builtin_amdgcn_mfma_i32_16x16x32_i8(__builtin_bit_cast(long, a6), B2, accZ, 0,0,0);
    accZ = __builtin_amdgcn_mfma_i32_16x16x32_i8(__builtin_bit_cast(long, a7), B3, accZ, 0,0,0);
    accN = __builtin_amdgcn_mfma_i32_16x16x32_i8(__builtin_bit_cast(long, a8), B0, accN, 0,0,0);
    accN = __builtin_amdgcn_mfma_i32_16x16x32_i8(__builtin_bit_cast(long, a9), B1, accN, 0,0,0);
    accN = __builtin_amdgcn_mfma_i32_16x16x32_i8(__builtin_bit_cast(long, a10), B2, accN, 0,0,0);
    accN = __builtin_amdgcn_mfma_i32_16x16x32_i8(__builtin_bit_cast(long, a11), B3, accN, 0,0,0);

    int tn2 = (t + 2 < T_) ? t + 2 : T_ - 1;
    int snl = (int)s_sid[tn2];

    lds_barrier();   // B1: s_x visible (h-frags already consumed)

    // ---- in-register epilogue: col-0 lanes own rows R..R+3 of all 3 gates ----
    if (colv){
      const int R = (w << 4) + (quad << 2);
      f32x4 scR = *reinterpret_cast<const f32x4*>(&s_scale[(0*NSW + sc) * H_ + R]);
      f32x4 scZ = *reinterpret_cast<const f32x4*>(&s_scale[(1*NSW + sc) * H_ + R]);
      f32x4 scN = *reinterpret_cast<const f32x4*>(&s_scale[(2*NSW + sc) * H_ + R]);
      f32x4 bR  = *reinterpret_cast<const f32x4*>(&s_b[(0*NSW + sc) * H_ + R]);
      f32x4 bZ  = *reinterpret_cast<const f32x4*>(&s_b[(1*NSW + sc) * H_ + R]);
      f32x4 bN  = *reinterpret_cast<const f32x4*>(&s_b[(2*NSW + sc) * H_ + R]);
      f32x4 xR  = *reinterpret_cast<const f32x4*>(&s_x[0*H_ + R]);
      f32x4 xZ  = *reinterpret_cast<const f32x4*>(&s_x[1*H_ + R]);
      f32x4 xN  = *reinterpret_cast<const f32x4*>(&s_x[2*H_ + R]);
      f32x4 hp  = *reinterpret_cast<const f32x4*>(&s_h[cur][R]);
      float mt  = s_mask[t];
      f32x4 hv;
      unsigned hq = 0;
      #pragma unroll
      for (int e = 0; e < 4; ++e){
        float hr = (float)accR[e] * scR[e] + bR[e];
        float hz = (float)accZ[e] * scZ[e] + bZ[e];
        float hn = (float)accN[e] * scN[e] + bN[e];
        float r = 1.f / (1.f + __expf(-(xR[e] + hr)));
        float z = 1.f / (1.f + __expf(-(xZ[e] + hz)));
        float ex = __expf(2.f * (xN[e] + r * hn));    // tanh via exp
        float n = 1.f - 2.f / (ex + 1.f);
        float hprev = hp[e];
        float hnew  = (1.f - z) * n + z * hprev;
        float ho    = mt * hnew + (1.f - mt) * hprev;
        hv[e] = ho;
        int qi = (int)rintf(ho * 127.f);
        qi = qi > 127 ? 127 : (qi < -127 ? -127 : qi);
        hq |= ((unsigned)(qi & 0xFF)) << (8 * e);
      }
      *reinterpret_cast<f32x4*>(&s_h[nxt][R]) = hv;
      *reinterpret_cast<unsigned*>(&s_hb8[nxt][R]) = hq;
    }

    lds_barrier();   // B2: h(t) visible

    // ---- logits (waves 0,1), overlaps next step's frag phase ----
    if (w < 2){
      float p = wo_a * s_h[nxt][L] + wo_b * s_h[nxt][64 + L];
      p += __shfl_down(p, 32); p += __shfl_down(p, 16); p += __shfl_down(p, 8);
      p += __shfl_down(p, 4);  p += __shfl_down(p, 2);  p += __shfl_down(p, 1);
      if (L == 0) outp[t * 2 + w] = p + bo_r;
    }

    sc = sn;
    sn = __builtin_amdgcn_readfirstlane(snl);
  }
}

extern "C" void kernel_launch(void* const* d_in, const int* in_sizes, int n_in,
                              void* d_out, int out_size, void* d_ws, size_t ws_size,
                              hipStream_t stream) {
  const float* stim = (const float*)d_in[0];
  const int*   swid = (const int*)  d_in[1];
  const float* mask = (const float*)d_in[2];
  const float* Win  = (const float*)d_in[3];
  const float* binp = (const float*)d_in[4];
  const float* Whr  = (const float*)d_in[5];
  const float* Whz  = (const float*)d_in[6];
  const float* Whn  = (const float*)d_in[7];
  const float* bhr  = (const float*)d_in[8];
  const float* bhz  = (const float*)d_in[9];
  const float* bhn  = (const float*)d_in[10];
  const float* Wo   = (const float*)d_in[11];
  const float* bo   = (const float*)d_in[12];

  uint2* wpk = (uint2*)d_ws;                       // 294912 B int8 images
  float* wsc = (float*)((char*)d_ws + 294912);     // 9216 B row scales

  pack_weights_i8<<<9, 256, 0, stream>>>(Whr, Whz, Whn, wpk, wsc);
  gru_run<<<B_, 512, 0, stream>>>(stim, swid, mask, Win, binp,
                                  bhr, bhz, bhn, Wo, bo, wpk, wsc, (float*)d_out);
}

// Round 17
// 763.916 us; speedup vs baseline: 1.4314x; 1.4314x over previous
//
#include <hip/hip_runtime.h>
#include <stdint.h>

#define B_  256
#define T_  512
#define H_  128
#define NSW 6
#define REPB 36864   // uint2 per replica image: 18 mats x 128 rows x 16 chunks = 294912 B

typedef __bf16 bf2_t  __attribute__((ext_vector_type(2)));
typedef int    i32x4  __attribute__((ext_vector_type(4)));
typedef float  f32x4  __attribute__((ext_vector_type(4)));

__device__ __forceinline__ unsigned short f2bf(float f){
  unsigned u = __float_as_uint(f);
  unsigned r = u + 0x7FFFu + ((u >> 16) & 1u);
  return (unsigned short)(r >> 16);
}
__device__ __forceinline__ unsigned pack2(float a, float b){
  return (unsigned)f2bf(a) | ((unsigned)f2bf(b) << 16);
}
__device__ __forceinline__ float dot2bf(unsigned wpair, unsigned hpair, float acc){
  return __builtin_amdgcn_fdot2_f32_bf16(__builtin_bit_cast(bf2_t, wpair),
                                         __builtin_bit_cast(bf2_t, hpair), acc, false);
}
__device__ __forceinline__ void lds_barrier(){
  asm volatile("s_waitcnt lgkmcnt(0)\ns_barrier" ::: "memory");
}

// int8 per-row quant into MFMA A-frag order, replicated nrep x (runtime).
// uint2 idx (within replica) = ((gs*2+hf)*16 + rg*4 + kc)*64 + q*16 + r,
// holds int8 W_g[s][row=hf*64+rg*16+r][k=kc*32+q*8+0..7]; gs = g*6+s.
// scales[gs*128+row] = amax/127^2 (single copy, after all replicas).
__global__ __launch_bounds__(256) void pack_weights_i8(const float* __restrict__ Wr,
                                                       const float* __restrict__ Wz,
                                                       const float* __restrict__ Wn,
                                                       uint2* __restrict__ dst,
                                                       float* __restrict__ scales,
                                                       int nrep){
  int idx = blockIdx.x * 256 + threadIdx.x;     // (gs, row)
  if (idx >= 18 * 128) return;
  int row = idx & 127;
  int gs  = idx >> 7;
  int s = gs % NSW, g = gs / NSW;
  const float* W = (g == 0) ? Wr : (g == 1) ? Wz : Wn;
  const float* src = W + (size_t)s * (H_*H_) + (size_t)row * H_;
  float amax = 0.f;
  for (int j = 0; j < H_; ++j) amax = fmaxf(amax, fabsf(src[j]));
  amax = fmaxf(amax, 1e-20f);
  float inv = 127.f / amax;
  scales[idx] = amax / 16129.f;
  int hf = row >> 6, rr = row & 63, rg = rr >> 4, r = rr & 15;
  for (int kc = 0; kc < 4; ++kc){
    for (int q = 0; q < 4; ++q){
      unsigned b0 = 0, b1 = 0;
      for (int e = 0; e < 8; ++e){
        int k = kc * 32 + q * 8 + e;
        int v = (int)rintf(src[k] * inv);
        v = v > 127 ? 127 : (v < -127 ? -127 : v);
        unsigned bv = (unsigned)(v & 0xFF);
        if (e < 4) b0 |= bv << (8 * e);
        else       b1 |= bv << (8 * (e - 4));
      }
      uint2 val = make_uint2(b0, b1);
      size_t o = ((size_t)(gs * 2 + hf) * 16 + rg * 4 + kc) * 64 + q * 16 + r;
      for (int rep = 0; rep < nrep; ++rep)
        dst[(size_t)rep * REPB + o] = val;
    }
  }
}

// 384 threads = 6 waves; wave w: gate g=w>>1, half hf=w&1. At-use int8 loads
// from this block's replica, 16 i8 MFMAs, LDS-merge epilogue (R13 structure).
__global__ __launch_bounds__(384, 1) void gru_run(const float* __restrict__ stim,
    const int*   __restrict__ swid,  const float* __restrict__ mask,
    const float* __restrict__ Win,   const float* __restrict__ binp,
    const float* __restrict__ b_hr,  const float* __restrict__ b_hz, const float* __restrict__ b_hn,
    const float* __restrict__ Wo,    const float* __restrict__ bo,
    const uint2* __restrict__ Wpk,   const float* __restrict__ Wsc,
    float* __restrict__ out, int repmask)
{
  const int b   = blockIdx.x;
  const int tid = threadIdx.x;
  const int w   = tid >> 6;
  const int L   = tid & 63;
  const int g   = w >> 1;
  const int hf  = w & 1;

  __shared__ uint4          s_stim2[T_];        // 8 KB  bf16 stim pairs
  __shared__ float          s_mask[T_];         // 2 KB
  __shared__ unsigned short s_sid[T_];          // 1 KB
  __shared__ float          s_b[3*NSW*H_];      // 9 KB
  __shared__ float          s_scale[3*NSW*H_];  // 9 KB
  __shared__ float          s_x[3*H_];          // 1.5 KB
  __shared__ float          s_acc[3*H_];        // 1.5 KB
  __shared__ float          s_h[H_];            // 0.5 KB
  __shared__ __align__(16) char s_hb8[160];     // h int8 [0,128) + zero pad

  // ---- init LDS ----
  for (int k = tid; k < T_; k += 384){
    const float* sp = stim + (size_t)b * T_ * 8 + (size_t)k * 8;
    uint4 o;
    o.x = pack2(sp[0], sp[1]); o.y = pack2(sp[2], sp[3]);
    o.z = pack2(sp[4], sp[5]); o.w = pack2(sp[6], sp[7]);
    s_stim2[k] = o;
    s_mask[k] = mask[(size_t)b * T_ + k];
    int ss = swid[(size_t)b * T_ + k];
    s_sid[k] = (unsigned short)(ss < 0 ? 0 : (ss > NSW - 1 ? NSW - 1 : ss));
  }
  for (int k = tid; k < 3 * NSW * H_; k += 384){
    int gg = k / (NSW * H_); int rr = k % (NSW * H_);
    const float* bp = (gg == 0) ? b_hr : (gg == 1) ? b_hz : b_hn;
    s_b[k] = bp[rr];
    s_scale[k] = Wsc[k];
  }
  if (tid < H_) s_h[tid] = 0.f;
  if (tid < 40) ((int*)s_hb8)[tid] = 0;

  unsigned winp[4];
  #pragma unroll
  for (int e = 0; e < 4; ++e)
    winp[e] = pack2(Win[(size_t)tid * 8 + 2*e], Win[(size_t)tid * 8 + 2*e + 1]);
  const float binr = binp[tid];

  float wo_a = 0.f, wo_b = 0.f, bo_r = 0.f;
  const int kk = (w == 3) ? 1 : 0;
  if (g == 1){
    wo_a = Wo[kk * H_ + L];
    wo_b = Wo[kk * H_ + 64 + L];
    bo_r = bo[kk];
  }

  // replica pick: blockIdx%8 ~ XCD, bits 3.. spread same-XCD CUs over replicas
  const int rep = (b >> 3) & repmask;
  const uint2* wbase = Wpk + (size_t)rep * REPB
                     + (size_t)g * 12288 + (size_t)hf * 1024 + L;

  const bool colv = (L & 15) == 0;
  const int  quad = L >> 4;
  float* outp = out + (size_t)b * T_ * 2;

  __syncthreads();

  #pragma unroll 1
  for (int t = 0; t < T_; ++t){
    int sc = __builtin_amdgcn_readfirstlane((int)s_sid[t]);

    // ---- at-use weight loads: 16 x dwordx2, stride 512 B ----
    const uint2* wp = wbase + (size_t)sc * 2048;
    uint2 A[16];
    #pragma unroll
    for (int j = 0; j < 16; ++j) A[j] = wp[j * 64];

    // B fragments: col-0 lanes read h int8 (8 B at k=kc*32+quad*8); rest zero pad
    long bl0, bl1, bl2, bl3;
    {
      int o0 = colv ? (0 * 32 + quad * 8) : 128;
      int o1 = colv ? (1 * 32 + quad * 8) : 128;
      int o2 = colv ? (2 * 32 + quad * 8) : 128;
      int o3 = colv ? (3 * 32 + quad * 8) : 128;
      bl0 = *(const long*)(s_hb8 + o0);
      bl1 = *(const long*)(s_hb8 + o1);
      bl2 = *(const long*)(s_hb8 + o2);
      bl3 = *(const long*)(s_hb8 + o3);
    }

    // input projection
    uint4 sp = s_stim2[t];
    float x = binr;
    x = dot2bf(winp[0], sp.x, x);
    x = dot2bf(winp[1], sp.y, x);
    x = dot2bf(winp[2], sp.z, x);
    x = dot2bf(winp[3], sp.w, x);
    s_x[tid] = x;

    // 16 i8 MFMAs
    i32x4 accv[4];
    #pragma unroll
    for (int rg = 0; rg < 4; ++rg){
      i32x4 a = {0, 0, 0, 0};
      a = __builtin_amdgcn_mfma_i32_16x16x32_i8(__builtin_bit_cast(long, A[rg*4+0]), bl0, a, 0, 0, 0);
      a = __builtin_amdgcn_mfma_i32_16x16x32_i8(__builtin_bit_cast(long, A[rg*4+1]), bl1, a, 0, 0, 0);
      a = __builtin_amdgcn_mfma_i32_16x16x32_i8(__builtin_bit_cast(long, A[rg*4+2]), bl2, a, 0, 0, 0);
      a = __builtin_amdgcn_mfma_i32_16x16x32_i8(__builtin_bit_cast(long, A[rg*4+3]), bl3, a, 0, 0, 0);
      accv[rg] = a;
    }

    // dequant + scatter: col-0 lanes own rows rg*16 + quad*4 + 0..3
    if (colv){
      #pragma unroll
      for (int rg = 0; rg < 4; ++rg){
        int rbase = hf * 64 + rg * 16 + quad * 4;
        f32x4 scf = *reinterpret_cast<const f32x4*>(&s_scale[(g * NSW + sc) * H_ + rbase]);
        f32x4 v;
        v.x = (float)accv[rg].x * scf.x;
        v.y = (float)accv[rg].y * scf.y;
        v.z = (float)accv[rg].z * scf.z;
        v.w = (float)accv[rg].w * scf.w;
        *reinterpret_cast<f32x4*>(&s_acc[g * H_ + rbase]) = v;
      }
    }

    lds_barrier();   // B1: s_acc + s_x visible

    if (tid < H_){
      const int i = tid;
      float hr = s_acc[i]        + s_b[0 * (NSW*H_) + sc * H_ + i];
      float hz = s_acc[H_ + i]   + s_b[1 * (NSW*H_) + sc * H_ + i];
      float hn = s_acc[2*H_ + i] + s_b[2 * (NSW*H_) + sc * H_ + i];
      float xr = s_x[i], xz = s_x[H_ + i], xn = s_x[2*H_ + i];
      float r = 1.f / (1.f + __expf(-(xr + hr)));
      float z = 1.f / (1.f + __expf(-(xz + hz)));
      float e = __expf(2.f * (xn + r * hn));       // tanh via exp
      float n = 1.f - 2.f / (e + 1.f);
      float hprev = s_h[i];
      float hnew  = (1.f - z) * n + z * hprev;
      float mt    = s_mask[t];
      float ho    = mt * hnew + (1.f - mt) * hprev;
      s_h[i] = ho;
      int qi = (int)rintf(ho * 127.f);
      qi = qi > 127 ? 127 : (qi < -127 ? -127 : qi);
      s_hb8[i] = (char)qi;
    }

    lds_barrier();   // B2: h visible

    if (g == 1){
      float p = wo_a * s_h[L] + wo_b * s_h[64 + L];
      p += __shfl_down(p, 32); p += __shfl_down(p, 16); p += __shfl_down(p, 8);
      p += __shfl_down(p, 4);  p += __shfl_down(p, 2);  p += __shfl_down(p, 1);
      if (L == 0) outp[t * 2 + kk] = p + bo_r;
    }
  }
}

extern "C" void kernel_launch(void* const* d_in, const int* in_sizes, int n_in,
                              void* d_out, int out_size, void* d_ws, size_t ws_size,
                              hipStream_t stream) {
  const float* stim = (const float*)d_in[0];
  const int*   swid = (const int*)  d_in[1];
  const float* mask = (const float*)d_in[2];
  const float* Win  = (const float*)d_in[3];
  const float* binp = (const float*)d_in[4];
  const float* Whr  = (const float*)d_in[5];
  const float* Whz  = (const float*)d_in[6];
  const float* Whn  = (const float*)d_in[7];
  const float* bhr  = (const float*)d_in[8];
  const float* bhz  = (const float*)d_in[9];
  const float* bhn  = (const float*)d_in[10];
  const float* Wo   = (const float*)d_in[11];
  const float* bo   = (const float*)d_in[12];

  // replica count: largest power of two (<=8) that fits ws_size alongside scales
  const size_t repbytes = (size_t)REPB * 8;   // 294912 B per replica
  int nrep = (int)((ws_size > 9216) ? (ws_size - 9216) / repbytes : 1);
  if (nrep >= 8) nrep = 8; else if (nrep >= 4) nrep = 4;
  else if (nrep >= 2) nrep = 2; else nrep = 1;

  uint2* wpk = (uint2*)d_ws;
  float* wsc = (float*)((char*)d_ws + (size_t)nrep * repbytes);

  pack_weights_i8<<<9, 256, 0, stream>>>(Whr, Whz, Whn, wpk, wsc, nrep);
  gru_run<<<B_, 384, 0, stream>>>(stim, swid, mask, Win, binp,
                                  bhr, bhz, bhn, Wo, bo, wpk, wsc, (float*)d_out,
                                  nrep - 1);
}